// Round 7
// baseline (950.436 us; speedup 1.0000x reference)
//
#include <hip/hip_runtime.h>
#include <hip/hip_cooperative_groups.h>

namespace cg = cooperative_groups;

// GCN: 3-layer, N=100000, E=1600000, feat 128->128->128->64, fp32 in/out.
// R6: (1) whole CSR-build+prep phase fused into ONE cooperative kernel with
// grid.sync() between phases (was 10 small dispatches -> launch-gap savings);
// (2) agg loops give each quad/oct a contiguous edge span, unrolled x4 with
// clamped+masked loads -> 4 gathers in flight on EVERY iteration (old code
// had a 1-deep tail that dominated at avg deg 17).
// Pipeline: split-bf16 MFMA GEMM (epilogue folds dis[row]) -> gather agg
// out[i] = dis[i]*(sum_e T'[col] + T'[i]) + bias, emits hi/lo bf16 split.

typedef __attribute__((ext_vector_type(8))) short bf16x8;
typedef __attribute__((ext_vector_type(4))) float floatx4;

// ---------------- helpers ----------------

__device__ inline unsigned short f2bf(float f) {
    union { float f; unsigned u; } v; v.f = f;
    unsigned r = v.u + 0x7fffu + ((v.u >> 16) & 1u);  // RNE
    return (unsigned short)(r >> 16);
}

__device__ inline float bf2f(unsigned short h) {
    union { unsigned u; float f; } v; v.u = (unsigned)h << 16;
    return v.f;
}

__device__ inline void split_bf(float v, unsigned short& h, unsigned short& l) {
    h = f2bf(v);
    l = f2bf(v - bf2f(h));
}

__device__ inline void bf2x_to_f(unsigned u, float& a, float& b) {
    union { unsigned x; float f; } lo, hi;
    lo.x = u << 16; hi.x = u & 0xffff0000u;
    a = lo.f; b = hi.f;
}

// acc += w * unpack(u)   (w = 1.0 or 0.0 mask)
__device__ inline void accw8(float* acc, uint4 u, float w) {
    float a, b;
    bf2x_to_f(u.x, a, b); acc[0] = fmaf(w, a, acc[0]); acc[1] = fmaf(w, b, acc[1]);
    bf2x_to_f(u.y, a, b); acc[2] = fmaf(w, a, acc[2]); acc[3] = fmaf(w, b, acc[3]);
    bf2x_to_f(u.z, a, b); acc[4] = fmaf(w, a, acc[4]); acc[5] = fmaf(w, b, acc[5]);
    bf2x_to_f(u.w, a, b); acc[6] = fmaf(w, a, acc[6]); acc[7] = fmaf(w, b, acc[7]);
}

// ---------------- fused cooperative build kernel ----------------
// Phases (grid.sync between): A zero deg | B histogram+rank | C chunk scan
// | D block-sum scan (block 0) | E rp+=boffs, dis | F scatter + prepX + prepW

__global__ __launch_bounds__(256) void k_build(
    const int* __restrict__ row, const int* __restrict__ col,
    const float* __restrict__ x,
    int* __restrict__ deg, int* __restrict__ pos, int* __restrict__ rp,
    int* __restrict__ csr, float* __restrict__ dis,
    unsigned short* __restrict__ Ahi, unsigned short* __restrict__ Alo,
    int* __restrict__ bsum, int* __restrict__ boffs,
    const float* __restrict__ W0, const float* __restrict__ W1,
    const float* __restrict__ W2,
    unsigned short* __restrict__ Wt0h, unsigned short* __restrict__ Wt0l,
    unsigned short* __restrict__ Wt1h, unsigned short* __restrict__ Wt1l,
    unsigned short* __restrict__ Wt2h, unsigned short* __restrict__ Wt2l,
    int n, int e, int nb) {
    cg::grid_group grid = cg::this_grid();
    const int tid = threadIdx.x;
    const int gsz = gridDim.x * blockDim.x;
    const int gid = blockIdx.x * blockDim.x + tid;
    __shared__ int s[512];

    // A: zero deg
    for (int i = gid; i < n; i += gsz) deg[i] = 0;
    grid.sync();

    // B: histogram + per-edge rank
    for (int i = gid; i < e; i += gsz) pos[i] = atomicAdd(&deg[row[i]], 1);
    grid.sync();

    // C: per-256-chunk exclusive scan (block b handles chunk b; nb <= gridDim)
    if (blockIdx.x < nb) {
        int i = blockIdx.x * 256 + tid;
        int v = (i < n) ? deg[i] : 0;
        s[tid] = v;
        __syncthreads();
        for (int off = 1; off < 256; off <<= 1) {
            int t = (tid >= off) ? s[tid - off] : 0;
            __syncthreads();
            s[tid] += t;
            __syncthreads();
        }
        if (i < n) rp[i] = s[tid] - v;
        if (tid == 255) bsum[blockIdx.x] = s[255];
    }
    grid.sync();

    // D: block 0 scans bsum[0..nb) (nb <= 512) with 256 threads, two halves
    if (blockIdx.x == 0) {
        int o0 = (tid < nb) ? bsum[tid] : 0;
        int o1 = (tid + 256 < nb) ? bsum[tid + 256] : 0;
        s[tid] = o0;
        s[tid + 256] = o1;
        __syncthreads();
        for (int off = 1; off < 256; off <<= 1) {
            int t = (tid >= off) ? s[tid - off] : 0;
            __syncthreads();
            s[tid] += t;
            __syncthreads();
        }
        int t0 = s[255];
        for (int off = 1; off < 256; off <<= 1) {
            int t = (tid >= off) ? s[256 + tid - off] : 0;
            __syncthreads();
            s[256 + tid] += t;
            __syncthreads();
        }
        boffs[tid] = s[tid] - o0;
        boffs[256 + tid] = s[256 + tid] + t0 - o1;
        if (tid == 0) rp[n] = t0 + s[511];
    }
    grid.sync();

    // E: add block offsets; dis
    for (int i = gid; i < n; i += gsz) {
        rp[i] += boffs[i >> 8];
        dis[i] = rsqrtf((float)(deg[i] + 1));
    }
    grid.sync();

    // F: atomic-free scatter + prepX + prepW (independent)
    for (int i = gid; i < e; i += gsz) {
        int r = row[i];
        csr[rp[r] + pos[i]] = col[i];
    }
    const int total4 = n * 32;  // float4 count of x
    for (int id = gid; id < total4; id += gsz) {
        float4 v = ((const float4*)x)[id];
        ushort4 h, l;
        split_bf(v.x, h.x, l.x);
        split_bf(v.y, h.y, l.y);
        split_bf(v.z, h.z, l.z);
        split_bf(v.w, h.w, l.w);
        ((ushort4*)Ahi)[id] = h;
        ((ushort4*)Alo)[id] = l;
    }
    for (int id = gid; id < 128 * 128; id += gsz) {
        int k = id >> 7, nn = id & 127;
        unsigned short h, l;
        split_bf(W0[id], h, l);
        Wt0h[nn * 128 + k] = h;
        Wt0l[nn * 128 + k] = l;
        split_bf(W1[id], h, l);
        Wt1h[nn * 128 + k] = h;
        Wt1l[nn * 128 + k] = l;
    }
    for (int id = gid; id < 128 * 64; id += gsz) {
        int k = id >> 6, nn = id & 63;
        unsigned short h, l;
        split_bf(W2[id], h, l);
        Wt2h[nn * 128 + k] = h;
        Wt2l[nn * 128 + k] = l;
    }
}

// ---------------- split-bf16 MFMA GEMM, epilogue scales by dis ----------------
// T'[r] = dis[r] * ((Ah+Al)[n x 128] @ W[128 x LDW])[r], bf16 out.
// Verified layouts: mfma_f32_16x16x32_bf16, A[m=lane&15][k=quad*8+j],
// C/D col=lane&15 row=quad*4+reg.

template <int NB>  // LDW = NB*64
__global__ __launch_bounds__(256) void k_gemm_mfma(
    const unsigned short* __restrict__ Ahi, const unsigned short* __restrict__ Alo,
    const unsigned short* __restrict__ Wthi, const unsigned short* __restrict__ Wtlo,
    const float* __restrict__ dis, unsigned short* __restrict__ T, int n) {
    const int LDW = NB * 64;
    __shared__ unsigned short Ah_s[64 * 128];
    __shared__ unsigned short Al_s[64 * 128];
    const int tid = threadIdx.x;
    const int bid = blockIdx.x;
    const int bx = (NB == 2) ? (bid >> 1) : bid;
    const int by = (NB == 2) ? (bid & 1) : 0;
    const int row0 = bx * 64;
    const int col0 = by * 64;

    const int wave = tid >> 6, lane = tid & 63;
    const int ln = lane & 15, quad = lane >> 4;
    const int m0 = (wave >> 1) * 32;
    const int nq0 = (wave & 1) * 32;

    bf16x8 Bh[4][2], Bl[4][2];
#pragma unroll
    for (int s = 0; s < 4; s++)
#pragma unroll
        for (int j = 0; j < 2; j++) {
            int ncol = col0 + nq0 + 16 * j + ln;
            int koff = 32 * s + quad * 8;
            Bh[s][j] = *(const bf16x8*)&Wthi[ncol * 128 + koff];
            Bl[s][j] = *(const bf16x8*)&Wtlo[ncol * 128 + koff];
        }

#pragma unroll
    for (int k = 0; k < 4; k++) {
        int id = k * 256 + tid;
        int r = id >> 4, c = id & 15;
        int gr = row0 + r;
        uint4 vh = make_uint4(0, 0, 0, 0), vl = make_uint4(0, 0, 0, 0);
        if (gr < n) {
            vh = *(const uint4*)&Ahi[(size_t)gr * 128 + c * 8];
            vl = *(const uint4*)&Alo[(size_t)gr * 128 + c * 8];
        }
        int pc = c ^ (r & 15);
        *(uint4*)&Ah_s[r * 128 + pc * 8] = vh;
        *(uint4*)&Al_s[r * 128 + pc * 8] = vl;
    }
    __syncthreads();

    floatx4 acc[2][2];
#pragma unroll
    for (int i = 0; i < 2; i++)
#pragma unroll
        for (int j = 0; j < 2; j++) acc[i][j] = (floatx4){0.f, 0.f, 0.f, 0.f};

#pragma unroll
    for (int s = 0; s < 4; s++) {
        bf16x8 ah[2], al[2];
#pragma unroll
        for (int i = 0; i < 2; i++) {
            int off = (m0 + 16 * i + ln) * 128 + ((4 * s + quad) ^ ln) * 8;
            ah[i] = *(const bf16x8*)&Ah_s[off];
            al[i] = *(const bf16x8*)&Al_s[off];
        }
#pragma unroll
        for (int i = 0; i < 2; i++)
#pragma unroll
            for (int j = 0; j < 2; j++) {
                acc[i][j] = __builtin_amdgcn_mfma_f32_16x16x32_bf16(
                    ah[i], Bh[s][j], acc[i][j], 0, 0, 0);
                acc[i][j] = __builtin_amdgcn_mfma_f32_16x16x32_bf16(
                    ah[i], Bl[s][j], acc[i][j], 0, 0, 0);
                acc[i][j] = __builtin_amdgcn_mfma_f32_16x16x32_bf16(
                    al[i], Bh[s][j], acc[i][j], 0, 0, 0);
            }
    }

#pragma unroll
    for (int i = 0; i < 2; i++)
#pragma unroll
        for (int reg = 0; reg < 4; reg++) {
            int gr = row0 + m0 + 16 * i + quad * 4 + reg;
            if (gr < n) {
                float ds = dis[gr];
#pragma unroll
                for (int j = 0; j < 2; j++) {
                    int gc = col0 + nq0 + 16 * j + ln;
                    T[(size_t)gr * LDW + gc] = f2bf(ds * acc[i][j][reg]);
                }
            }
        }
}

// ---------------- aggregation (bf16 T' in) ----------------
// Each quad (16 lanes x 16B = 256B row) owns a CONTIGUOUS span of
// ceil(deg/4) edges; unroll x4 with clamped+masked loads -> 4 gathers in
// flight every iteration. acc = sum_e T'[col]; out = dis[i]*(acc+T'[i])+b.

__global__ void k_agg128(const unsigned short* __restrict__ T,
                         unsigned short* __restrict__ Ohi,
                         unsigned short* __restrict__ Olo,
                         const int* __restrict__ rp, const int* __restrict__ cols,
                         const float* __restrict__ dis, const float* __restrict__ bias,
                         int n) {
    int wid = (blockIdx.x * blockDim.x + threadIdx.x) >> 6;
    int lane = threadIdx.x & 63;
    if (wid >= n) return;
    const int quad = lane >> 4;
    const int fl = (lane & 15) * 8;
    int beg = rp[wid], end = rp[wid + 1];
    int deg = end - beg;
    int span = (deg + 3) >> 2;
    int qb = beg + quad * span;
    int qe = qb + span;
    if (qe > end) qe = end;

    float acc[8] = {0.f, 0.f, 0.f, 0.f, 0.f, 0.f, 0.f, 0.f};
    for (int e = qb; e < qe; e += 4) {
        int l = qe - 1;
        int i1 = e + 1, i2 = e + 2, i3 = e + 3;
        int c0 = cols[e];
        int c1 = cols[i1 < l ? i1 : l];
        int c2 = cols[i2 < l ? i2 : l];
        int c3 = cols[i3 < l ? i3 : l];
        float m1 = (i1 < qe) ? 1.f : 0.f;
        float m2 = (i2 < qe) ? 1.f : 0.f;
        float m3 = (i3 < qe) ? 1.f : 0.f;
        uint4 u0 = *(const uint4*)&T[(size_t)c0 * 128 + fl];
        uint4 u1 = *(const uint4*)&T[(size_t)c1 * 128 + fl];
        uint4 u2 = *(const uint4*)&T[(size_t)c2 * 128 + fl];
        uint4 u3 = *(const uint4*)&T[(size_t)c3 * 128 + fl];
        accw8(acc, u0, 1.f);
        accw8(acc, u1, m1);
        accw8(acc, u2, m2);
        accw8(acc, u3, m3);
    }
#pragma unroll
    for (int k = 0; k < 8; k++) {
        acc[k] += __shfl_xor(acc[k], 16);
        acc[k] += __shfl_xor(acc[k], 32);
    }
    if (quad == 0) {
        uint4 us = *(const uint4*)&T[(size_t)wid * 128 + fl];
        accw8(acc, us, 1.f);  // self term (already dis-scaled)
        float di = dis[wid];
        float4 bA = *(const float4*)&bias[fl];
        float4 bB = *(const float4*)&bias[fl + 4];
        float bb[8] = {bA.x, bA.y, bA.z, bA.w, bB.x, bB.y, bB.z, bB.w};
        unsigned short h[8], l[8];
#pragma unroll
        for (int k = 0; k < 8; k++) {
            float o = fmaf(di, acc[k], bb[k]);
            o = fmaxf(o, 0.f);  // relu (both 128-wide layers)
            split_bf(o, h[k], l[k]);
        }
        ushort4 h0 = {h[0], h[1], h[2], h[3]}, h1 = {h[4], h[5], h[6], h[7]};
        ushort4 l0 = {l[0], l[1], l[2], l[3]}, l1 = {l[4], l[5], l[6], l[7]};
        *(ushort4*)&Ohi[(size_t)wid * 128 + fl] = h0;
        *(ushort4*)&Ohi[(size_t)wid * 128 + fl + 4] = h1;
        *(ushort4*)&Olo[(size_t)wid * 128 + fl] = l0;
        *(ushort4*)&Olo[(size_t)wid * 128 + fl + 4] = l1;
    }
}

__global__ void k_agg64(const unsigned short* __restrict__ T, float* __restrict__ O,
                        const int* __restrict__ rp, const int* __restrict__ cols,
                        const float* __restrict__ dis, const float* __restrict__ bias,
                        int n) {
    int wid = (blockIdx.x * blockDim.x + threadIdx.x) >> 6;
    int lane = threadIdx.x & 63;
    if (wid >= n) return;
    const int oct = lane >> 3;
    const int fl = (lane & 7) * 8;
    int beg = rp[wid], end = rp[wid + 1];
    int deg = end - beg;
    int span = (deg + 7) >> 3;
    int qb = beg + oct * span;
    int qe = qb + span;
    if (qe > end) qe = end;

    float acc[8] = {0.f, 0.f, 0.f, 0.f, 0.f, 0.f, 0.f, 0.f};
    for (int e = qb; e < qe; e += 4) {
        int l = qe - 1;
        int i1 = e + 1, i2 = e + 2, i3 = e + 3;
        int c0 = cols[e];
        int c1 = cols[i1 < l ? i1 : l];
        int c2 = cols[i2 < l ? i2 : l];
        int c3 = cols[i3 < l ? i3 : l];
        float m1 = (i1 < qe) ? 1.f : 0.f;
        float m2 = (i2 < qe) ? 1.f : 0.f;
        float m3 = (i3 < qe) ? 1.f : 0.f;
        uint4 u0 = *(const uint4*)&T[(size_t)c0 * 64 + fl];
        uint4 u1 = *(const uint4*)&T[(size_t)c1 * 64 + fl];
        uint4 u2 = *(const uint4*)&T[(size_t)c2 * 64 + fl];
        uint4 u3 = *(const uint4*)&T[(size_t)c3 * 64 + fl];
        accw8(acc, u0, 1.f);
        accw8(acc, u1, m1);
        accw8(acc, u2, m2);
        accw8(acc, u3, m3);
    }
#pragma unroll
    for (int k = 0; k < 8; k++) {
        acc[k] += __shfl_xor(acc[k], 8);
        acc[k] += __shfl_xor(acc[k], 16);
        acc[k] += __shfl_xor(acc[k], 32);
    }
    if (oct == 0) {
        uint4 us = *(const uint4*)&T[(size_t)wid * 64 + fl];
        accw8(acc, us, 1.f);  // self term
        float di = dis[wid];
        float4 bA = *(const float4*)&bias[fl];
        float4 bB = *(const float4*)&bias[fl + 4];
        float bb[8] = {bA.x, bA.y, bA.z, bA.w, bB.x, bB.y, bB.z, bB.w};
        float o[8];
#pragma unroll
        for (int k = 0; k < 8; k++)
            o[k] = fmaf(di, acc[k], bb[k]);
        *(float4*)&O[(size_t)wid * 64 + fl] = make_float4(o[0], o[1], o[2], o[3]);
        *(float4*)&O[(size_t)wid * 64 + fl + 4] = make_float4(o[4], o[5], o[6], o[7]);
    }
}

// ---------------- launch ----------------

static inline char* align256(char* p) {
    return (char*)(((uintptr_t)p + 255) & ~(uintptr_t)255);
}

extern "C" void kernel_launch(void* const* d_in, const int* in_sizes, int n_in,
                              void* d_out, int out_size, void* d_ws, size_t ws_size,
                              hipStream_t stream) {
    const float* x  = (const float*)d_in[0];
    const int*   ei = (const int*)d_in[1];
    const float* W0 = (const float*)d_in[2];
    const float* b0 = (const float*)d_in[3];
    const float* W1 = (const float*)d_in[4];
    const float* b1 = (const float*)d_in[5];
    const float* W2 = (const float*)d_in[6];
    const float* b2 = (const float*)d_in[7];

    int Nn = in_sizes[0] / 128;
    int Ee = in_sizes[1] / 2;
    const int* rowI = ei;
    const int* colI = ei + Ee;

    char* p = (char*)d_ws;
    unsigned short* Tb  = (unsigned short*)p; p += (size_t)Nn * 128 * 2; p = align256(p);
    unsigned short* Ahi = (unsigned short*)p; p += (size_t)Nn * 128 * 2; p = align256(p);
    unsigned short* Alo = (unsigned short*)p; p += (size_t)Nn * 128 * 2; p = align256(p);
    int* csr    = (int*)p;   p += (size_t)Ee * 4;       p = align256(p);
    int* pos    = (int*)p;   p += (size_t)Ee * 4;       p = align256(p);
    int* rp     = (int*)p;   p += (size_t)(Nn + 1) * 4; p = align256(p);
    int* deg    = (int*)p;   p += (size_t)Nn * 4;       p = align256(p);
    float* dis  = (float*)p; p += (size_t)Nn * 4;       p = align256(p);
    int* bsum   = (int*)p;   p += 512 * 4;
    int* boffs  = (int*)p;   p += 512 * 4;
    unsigned short* Wt0h = (unsigned short*)p; p += 128 * 128 * 2;
    unsigned short* Wt0l = (unsigned short*)p; p += 128 * 128 * 2;
    unsigned short* Wt1h = (unsigned short*)p; p += 128 * 128 * 2;
    unsigned short* Wt1l = (unsigned short*)p; p += 128 * 128 * 2;
    unsigned short* Wt2h = (unsigned short*)p; p += 64 * 128 * 2;
    unsigned short* Wt2l = (unsigned short*)p; p += 64 * 128 * 2;

    int nb = (Nn + 255) / 256;  // scan chunks (<= 512 and <= grid)

    void* args[] = {
        (void*)&rowI, (void*)&colI, (void*)&x,
        (void*)&deg, (void*)&pos, (void*)&rp, (void*)&csr, (void*)&dis,
        (void*)&Ahi, (void*)&Alo, (void*)&bsum, (void*)&boffs,
        (void*)&W0, (void*)&W1, (void*)&W2,
        (void*)&Wt0h, (void*)&Wt0l, (void*)&Wt1h, (void*)&Wt1l,
        (void*)&Wt2h, (void*)&Wt2l,
        (void*)&Nn, (void*)&Ee, (void*)&nb};
    hipLaunchCooperativeKernel((const void*)k_build, dim3(1024), dim3(256),
                               args, 0, stream);

    const int gx = (Nn + 63) / 64;
    const int ab = (Nn + 3) / 4;  // 4 waves (nodes) per 256-thread block

    k_gemm_mfma<2><<<2 * gx, 256, 0, stream>>>(Ahi, Alo, Wt0h, Wt0l, dis, Tb, Nn);
    k_agg128<<<ab, 256, 0, stream>>>(Tb, Ahi, Alo, rp, csr, dis, b0, Nn);
    k_gemm_mfma<2><<<2 * gx, 256, 0, stream>>>(Ahi, Alo, Wt1h, Wt1l, dis, Tb, Nn);
    k_agg128<<<ab, 256, 0, stream>>>(Tb, Ahi, Alo, rp, csr, dis, b1, Nn);
    k_gemm_mfma<1><<<gx, 256, 0, stream>>>(Ahi, Alo, Wt2h, Wt2l, dis, Tb, Nn);
    k_agg64<<<ab, 256, 0, stream>>>(Tb, (float*)d_out, rp, csr, dis, b2, Nn);
}

// Round 8
// 483.115 us; speedup vs baseline: 1.9673x; 1.9673x over previous
//
#include <hip/hip_runtime.h>

// GCN: 3-layer, N=100000, E=1600000, feat 128->128->128->64, fp32 in/out.
// R8: revert R7's cooperative k_build (grid.sync costs ~100us/sync on 8-XCD
// MI355X -- measured 577us for the fused build vs ~200us split). Keep R7's
// span-based agg (contiguous per-quad spans, 4 masked gathers in flight every
// iter). Fuse dis into scan1; fuse prepX+prepW into one k_prep.
// Pipeline: split-bf16 MFMA GEMM (epilogue folds dis[row]) -> gather agg
// out[i] = dis[i]*(sum_e T'[col] + T'[i]) + bias, emits hi/lo bf16 split.

typedef __attribute__((ext_vector_type(8))) short bf16x8;
typedef __attribute__((ext_vector_type(4))) float floatx4;

// ---------------- helpers ----------------

__device__ inline unsigned short f2bf(float f) {
    union { float f; unsigned u; } v; v.f = f;
    unsigned r = v.u + 0x7fffu + ((v.u >> 16) & 1u);  // RNE
    return (unsigned short)(r >> 16);
}

__device__ inline float bf2f(unsigned short h) {
    union { unsigned u; float f; } v; v.u = (unsigned)h << 16;
    return v.f;
}

__device__ inline void split_bf(float v, unsigned short& h, unsigned short& l) {
    h = f2bf(v);
    l = f2bf(v - bf2f(h));
}

__device__ inline void bf2x_to_f(unsigned u, float& a, float& b) {
    union { unsigned x; float f; } lo, hi;
    lo.x = u << 16; hi.x = u & 0xffff0000u;
    a = lo.f; b = hi.f;
}

// acc += w * unpack(u)   (w = 1.0 or 0.0 mask)
__device__ inline void accw8(float* acc, uint4 u, float w) {
    float a, b;
    bf2x_to_f(u.x, a, b); acc[0] = fmaf(w, a, acc[0]); acc[1] = fmaf(w, b, acc[1]);
    bf2x_to_f(u.y, a, b); acc[2] = fmaf(w, a, acc[2]); acc[3] = fmaf(w, b, acc[3]);
    bf2x_to_f(u.z, a, b); acc[4] = fmaf(w, a, acc[4]); acc[5] = fmaf(w, b, acc[5]);
    bf2x_to_f(u.w, a, b); acc[6] = fmaf(w, a, acc[6]); acc[7] = fmaf(w, b, acc[7]);
}

// ---------------- CSR build ----------------

__global__ void k_count(const int* __restrict__ row, int* __restrict__ deg,
                        int* __restrict__ pos, int e) {
    int i = blockIdx.x * blockDim.x + threadIdx.x;
    if (i < e) pos[i] = atomicAdd(&deg[row[i]], 1);
}

// exclusive scan of 256-chunk + dis computation (deg already loaded)
__global__ void k_scan1(const int* __restrict__ deg, int* __restrict__ rp,
                        int* __restrict__ bsum, float* __restrict__ dis, int n) {
    __shared__ int s[256];
    int tid = threadIdx.x;
    int i = blockIdx.x * 256 + tid;
    int v = (i < n) ? deg[i] : 0;
    if (i < n) dis[i] = rsqrtf((float)(v + 1));  // +1 self-loop
    s[tid] = v;
    __syncthreads();
    for (int off = 1; off < 256; off <<= 1) {
        int t = (tid >= off) ? s[tid - off] : 0;
        __syncthreads();
        s[tid] += t;
        __syncthreads();
    }
    if (i < n) rp[i] = s[tid] - v;
    if (tid == 255) bsum[blockIdx.x] = s[255];
}

__global__ void k_scan2(const int* __restrict__ bsum, int* __restrict__ boffs,
                        int nb, int* __restrict__ rp, int n, int total) {
    __shared__ int s[512];
    int tid = threadIdx.x;
    int v = (tid < nb) ? bsum[tid] : 0;
    s[tid] = v;
    __syncthreads();
    for (int off = 1; off < 512; off <<= 1) {
        int t = (tid >= off) ? s[tid - off] : 0;
        __syncthreads();
        s[tid] += t;
        __syncthreads();
    }
    if (tid < nb) boffs[tid] = s[tid] - v;
    if (tid == 0) rp[n] = total;
}

__global__ void k_scan3(int* __restrict__ rp, const int* __restrict__ boffs, int n) {
    int i = blockIdx.x * blockDim.x + threadIdx.x;
    if (i < n) rp[i] += boffs[i >> 8];
}

__global__ void k_scatter(const int* __restrict__ row, const int* __restrict__ col,
                          const int* __restrict__ rp, const int* __restrict__ pos,
                          int* __restrict__ csr, int e) {
    int i = blockIdx.x * blockDim.x + threadIdx.x;
    if (i < e) {
        int r = row[i];
        csr[rp[r] + pos[i]] = col[i];
    }
}

// ---------------- fused prep: X split + all three W transposes ----------------

__global__ void k_prep(const float* __restrict__ X, unsigned short* __restrict__ Xhi,
                       unsigned short* __restrict__ Xlo,
                       const float* __restrict__ W0, const float* __restrict__ W1,
                       const float* __restrict__ W2,
                       unsigned short* __restrict__ Wt0h, unsigned short* __restrict__ Wt0l,
                       unsigned short* __restrict__ Wt1h, unsigned short* __restrict__ Wt1l,
                       unsigned short* __restrict__ Wt2h, unsigned short* __restrict__ Wt2l,
                       int total4) {
    int gid = blockIdx.x * blockDim.x + threadIdx.x;
    int gsz = gridDim.x * blockDim.x;
    for (int id = gid; id < total4; id += gsz) {
        float4 v = ((const float4*)X)[id];
        ushort4 h, l;
        split_bf(v.x, h.x, l.x);
        split_bf(v.y, h.y, l.y);
        split_bf(v.z, h.z, l.z);
        split_bf(v.w, h.w, l.w);
        ((ushort4*)Xhi)[id] = h;
        ((ushort4*)Xlo)[id] = l;
    }
    for (int id = gid; id < 128 * 128; id += gsz) {
        int k = id >> 7, nn = id & 127;
        unsigned short h, l;
        split_bf(W0[id], h, l);
        Wt0h[nn * 128 + k] = h;
        Wt0l[nn * 128 + k] = l;
        split_bf(W1[id], h, l);
        Wt1h[nn * 128 + k] = h;
        Wt1l[nn * 128 + k] = l;
    }
    for (int id = gid; id < 128 * 64; id += gsz) {
        int k = id >> 6, nn = id & 63;
        unsigned short h, l;
        split_bf(W2[id], h, l);
        Wt2h[nn * 128 + k] = h;
        Wt2l[nn * 128 + k] = l;
    }
}

// ---------------- split-bf16 MFMA GEMM, epilogue scales by dis ----------------
// T'[r] = dis[r] * ((Ah+Al)[n x 128] @ W[128 x LDW])[r], bf16 out.
// Verified layouts: mfma_f32_16x16x32_bf16, A[m=lane&15][k=quad*8+j],
// C/D col=lane&15 row=quad*4+reg.

template <int NB>  // LDW = NB*64
__global__ __launch_bounds__(256) void k_gemm_mfma(
    const unsigned short* __restrict__ Ahi, const unsigned short* __restrict__ Alo,
    const unsigned short* __restrict__ Wthi, const unsigned short* __restrict__ Wtlo,
    const float* __restrict__ dis, unsigned short* __restrict__ T, int n) {
    const int LDW = NB * 64;
    __shared__ unsigned short Ah_s[64 * 128];
    __shared__ unsigned short Al_s[64 * 128];
    const int tid = threadIdx.x;
    const int bid = blockIdx.x;
    const int bx = (NB == 2) ? (bid >> 1) : bid;
    const int by = (NB == 2) ? (bid & 1) : 0;
    const int row0 = bx * 64;
    const int col0 = by * 64;

    const int wave = tid >> 6, lane = tid & 63;
    const int ln = lane & 15, quad = lane >> 4;
    const int m0 = (wave >> 1) * 32;
    const int nq0 = (wave & 1) * 32;

    bf16x8 Bh[4][2], Bl[4][2];
#pragma unroll
    for (int s = 0; s < 4; s++)
#pragma unroll
        for (int j = 0; j < 2; j++) {
            int ncol = col0 + nq0 + 16 * j + ln;
            int koff = 32 * s + quad * 8;
            Bh[s][j] = *(const bf16x8*)&Wthi[ncol * 128 + koff];
            Bl[s][j] = *(const bf16x8*)&Wtlo[ncol * 128 + koff];
        }

#pragma unroll
    for (int k = 0; k < 4; k++) {
        int id = k * 256 + tid;
        int r = id >> 4, c = id & 15;
        int gr = row0 + r;
        uint4 vh = make_uint4(0, 0, 0, 0), vl = make_uint4(0, 0, 0, 0);
        if (gr < n) {
            vh = *(const uint4*)&Ahi[(size_t)gr * 128 + c * 8];
            vl = *(const uint4*)&Alo[(size_t)gr * 128 + c * 8];
        }
        int pc = c ^ (r & 15);
        *(uint4*)&Ah_s[r * 128 + pc * 8] = vh;
        *(uint4*)&Al_s[r * 128 + pc * 8] = vl;
    }
    __syncthreads();

    floatx4 acc[2][2];
#pragma unroll
    for (int i = 0; i < 2; i++)
#pragma unroll
        for (int j = 0; j < 2; j++) acc[i][j] = (floatx4){0.f, 0.f, 0.f, 0.f};

#pragma unroll
    for (int s = 0; s < 4; s++) {
        bf16x8 ah[2], al[2];
#pragma unroll
        for (int i = 0; i < 2; i++) {
            int off = (m0 + 16 * i + ln) * 128 + ((4 * s + quad) ^ ln) * 8;
            ah[i] = *(const bf16x8*)&Ah_s[off];
            al[i] = *(const bf16x8*)&Al_s[off];
        }
#pragma unroll
        for (int i = 0; i < 2; i++)
#pragma unroll
            for (int j = 0; j < 2; j++) {
                acc[i][j] = __builtin_amdgcn_mfma_f32_16x16x32_bf16(
                    ah[i], Bh[s][j], acc[i][j], 0, 0, 0);
                acc[i][j] = __builtin_amdgcn_mfma_f32_16x16x32_bf16(
                    ah[i], Bl[s][j], acc[i][j], 0, 0, 0);
                acc[i][j] = __builtin_amdgcn_mfma_f32_16x16x32_bf16(
                    al[i], Bh[s][j], acc[i][j], 0, 0, 0);
            }
    }

#pragma unroll
    for (int i = 0; i < 2; i++)
#pragma unroll
        for (int reg = 0; reg < 4; reg++) {
            int gr = row0 + m0 + 16 * i + quad * 4 + reg;
            if (gr < n) {
                float ds = dis[gr];
#pragma unroll
                for (int j = 0; j < 2; j++) {
                    int gc = col0 + nq0 + 16 * j + ln;
                    T[(size_t)gr * LDW + gc] = f2bf(ds * acc[i][j][reg]);
                }
            }
        }
}

// ---------------- aggregation (bf16 T' in) ----------------
// Each quad (16 lanes x 16B = 256B row) owns a CONTIGUOUS span of
// ceil(deg/4) edges; unroll x4 with clamped+masked loads -> 4 gathers in
// flight every iteration. acc = sum_e T'[col]; out = dis[i]*(acc+T'[i])+b.

__global__ void k_agg128(const unsigned short* __restrict__ T,
                         unsigned short* __restrict__ Ohi,
                         unsigned short* __restrict__ Olo,
                         const int* __restrict__ rp, const int* __restrict__ cols,
                         const float* __restrict__ dis, const float* __restrict__ bias,
                         int n) {
    int wid = (blockIdx.x * blockDim.x + threadIdx.x) >> 6;
    int lane = threadIdx.x & 63;
    if (wid >= n) return;
    const int quad = lane >> 4;
    const int fl = (lane & 15) * 8;
    int beg = rp[wid], end = rp[wid + 1];
    int deg = end - beg;
    int span = (deg + 3) >> 2;
    int qb = beg + quad * span;
    int qe = qb + span;
    if (qe > end) qe = end;

    float acc[8] = {0.f, 0.f, 0.f, 0.f, 0.f, 0.f, 0.f, 0.f};
    for (int e = qb; e < qe; e += 4) {
        int l = qe - 1;
        int i1 = e + 1, i2 = e + 2, i3 = e + 3;
        int c0 = cols[e];
        int c1 = cols[i1 < l ? i1 : l];
        int c2 = cols[i2 < l ? i2 : l];
        int c3 = cols[i3 < l ? i3 : l];
        float m1 = (i1 < qe) ? 1.f : 0.f;
        float m2 = (i2 < qe) ? 1.f : 0.f;
        float m3 = (i3 < qe) ? 1.f : 0.f;
        uint4 u0 = *(const uint4*)&T[(size_t)c0 * 128 + fl];
        uint4 u1 = *(const uint4*)&T[(size_t)c1 * 128 + fl];
        uint4 u2 = *(const uint4*)&T[(size_t)c2 * 128 + fl];
        uint4 u3 = *(const uint4*)&T[(size_t)c3 * 128 + fl];
        accw8(acc, u0, 1.f);
        accw8(acc, u1, m1);
        accw8(acc, u2, m2);
        accw8(acc, u3, m3);
    }
#pragma unroll
    for (int k = 0; k < 8; k++) {
        acc[k] += __shfl_xor(acc[k], 16);
        acc[k] += __shfl_xor(acc[k], 32);
    }
    if (quad == 0) {
        uint4 us = *(const uint4*)&T[(size_t)wid * 128 + fl];
        accw8(acc, us, 1.f);  // self term (already dis-scaled)
        float di = dis[wid];
        float4 bA = *(const float4*)&bias[fl];
        float4 bB = *(const float4*)&bias[fl + 4];
        float bb[8] = {bA.x, bA.y, bA.z, bA.w, bB.x, bB.y, bB.z, bB.w};
        unsigned short h[8], l[8];
#pragma unroll
        for (int k = 0; k < 8; k++) {
            float o = fmaf(di, acc[k], bb[k]);
            o = fmaxf(o, 0.f);  // relu (both 128-wide layers)
            split_bf(o, h[k], l[k]);
        }
        ushort4 h0 = {h[0], h[1], h[2], h[3]}, h1 = {h[4], h[5], h[6], h[7]};
        ushort4 l0 = {l[0], l[1], l[2], l[3]}, l1 = {l[4], l[5], l[6], l[7]};
        *(ushort4*)&Ohi[(size_t)wid * 128 + fl] = h0;
        *(ushort4*)&Ohi[(size_t)wid * 128 + fl + 4] = h1;
        *(ushort4*)&Olo[(size_t)wid * 128 + fl] = l0;
        *(ushort4*)&Olo[(size_t)wid * 128 + fl + 4] = l1;
    }
}

__global__ void k_agg64(const unsigned short* __restrict__ T, float* __restrict__ O,
                        const int* __restrict__ rp, const int* __restrict__ cols,
                        const float* __restrict__ dis, const float* __restrict__ bias,
                        int n) {
    int wid = (blockIdx.x * blockDim.x + threadIdx.x) >> 6;
    int lane = threadIdx.x & 63;
    if (wid >= n) return;
    const int oct = lane >> 3;
    const int fl = (lane & 7) * 8;
    int beg = rp[wid], end = rp[wid + 1];
    int deg = end - beg;
    int span = (deg + 7) >> 3;
    int qb = beg + oct * span;
    int qe = qb + span;
    if (qe > end) qe = end;

    float acc[8] = {0.f, 0.f, 0.f, 0.f, 0.f, 0.f, 0.f, 0.f};
    for (int e = qb; e < qe; e += 4) {
        int l = qe - 1;
        int i1 = e + 1, i2 = e + 2, i3 = e + 3;
        int c0 = cols[e];
        int c1 = cols[i1 < l ? i1 : l];
        int c2 = cols[i2 < l ? i2 : l];
        int c3 = cols[i3 < l ? i3 : l];
        float m1 = (i1 < qe) ? 1.f : 0.f;
        float m2 = (i2 < qe) ? 1.f : 0.f;
        float m3 = (i3 < qe) ? 1.f : 0.f;
        uint4 u0 = *(const uint4*)&T[(size_t)c0 * 64 + fl];
        uint4 u1 = *(const uint4*)&T[(size_t)c1 * 64 + fl];
        uint4 u2 = *(const uint4*)&T[(size_t)c2 * 64 + fl];
        uint4 u3 = *(const uint4*)&T[(size_t)c3 * 64 + fl];
        accw8(acc, u0, 1.f);
        accw8(acc, u1, m1);
        accw8(acc, u2, m2);
        accw8(acc, u3, m3);
    }
#pragma unroll
    for (int k = 0; k < 8; k++) {
        acc[k] += __shfl_xor(acc[k], 8);
        acc[k] += __shfl_xor(acc[k], 16);
        acc[k] += __shfl_xor(acc[k], 32);
    }
    if (oct == 0) {
        uint4 us = *(const uint4*)&T[(size_t)wid * 64 + fl];
        accw8(acc, us, 1.f);  // self term
        float di = dis[wid];
        float4 bA = *(const float4*)&bias[fl];
        float4 bB = *(const float4*)&bias[fl + 4];
        float bb[8] = {bA.x, bA.y, bA.z, bA.w, bB.x, bB.y, bB.z, bB.w};
        float o[8];
#pragma unroll
        for (int k = 0; k < 8; k++)
            o[k] = fmaf(di, acc[k], bb[k]);
        *(float4*)&O[(size_t)wid * 64 + fl] = make_float4(o[0], o[1], o[2], o[3]);
        *(float4*)&O[(size_t)wid * 64 + fl + 4] = make_float4(o[4], o[5], o[6], o[7]);
    }
}

// ---------------- launch ----------------

static inline char* align256(char* p) {
    return (char*)(((uintptr_t)p + 255) & ~(uintptr_t)255);
}

extern "C" void kernel_launch(void* const* d_in, const int* in_sizes, int n_in,
                              void* d_out, int out_size, void* d_ws, size_t ws_size,
                              hipStream_t stream) {
    const float* x  = (const float*)d_in[0];
    const int*   ei = (const int*)d_in[1];
    const float* W0 = (const float*)d_in[2];
    const float* b0 = (const float*)d_in[3];
    const float* W1 = (const float*)d_in[4];
    const float* b1 = (const float*)d_in[5];
    const float* W2 = (const float*)d_in[6];
    const float* b2 = (const float*)d_in[7];

    const int Nn = in_sizes[0] / 128;
    const int Ee = in_sizes[1] / 2;
    const int* rowI = ei;
    const int* colI = ei + Ee;

    char* p = (char*)d_ws;
    unsigned short* Tb  = (unsigned short*)p; p += (size_t)Nn * 128 * 2; p = align256(p);
    unsigned short* Ahi = (unsigned short*)p; p += (size_t)Nn * 128 * 2; p = align256(p);
    unsigned short* Alo = (unsigned short*)p; p += (size_t)Nn * 128 * 2; p = align256(p);
    int* csr    = (int*)p;   p += (size_t)Ee * 4;       p = align256(p);
    int* pos    = (int*)p;   p += (size_t)Ee * 4;       p = align256(p);
    int* rp     = (int*)p;   p += (size_t)(Nn + 1) * 4; p = align256(p);
    int* deg    = (int*)p;   p += (size_t)Nn * 4;       p = align256(p);
    float* dis  = (float*)p; p += (size_t)Nn * 4;       p = align256(p);
    int* bsum   = (int*)p;   p += 512 * 4;
    int* boffs  = (int*)p;   p += 512 * 4;
    unsigned short* Wt0h = (unsigned short*)p; p += 128 * 128 * 2;
    unsigned short* Wt0l = (unsigned short*)p; p += 128 * 128 * 2;
    unsigned short* Wt1h = (unsigned short*)p; p += 128 * 128 * 2;
    unsigned short* Wt1l = (unsigned short*)p; p += 128 * 128 * 2;
    unsigned short* Wt2h = (unsigned short*)p; p += 64 * 128 * 2;
    unsigned short* Wt2l = (unsigned short*)p; p += 64 * 128 * 2;

    const int eb = (Ee + 255) / 256;
    const int nb = (Nn + 255) / 256;

    hipMemsetAsync(deg, 0, (size_t)Nn * 4, stream);

    k_count<<<eb, 256, 0, stream>>>(rowI, deg, pos, Ee);
    k_scan1<<<nb, 256, 0, stream>>>(deg, rp, bsum, dis, Nn);
    k_scan2<<<1, 512, 0, stream>>>(bsum, boffs, nb, rp, Nn, Ee);
    k_scan3<<<nb, 256, 0, stream>>>(rp, boffs, Nn);
    k_scatter<<<eb, 256, 0, stream>>>(rowI, colI, rp, pos, csr, Ee);
    k_prep<<<512, 256, 0, stream>>>(x, Ahi, Alo, W0, W1, W2,
                                    Wt0h, Wt0l, Wt1h, Wt1l, Wt2h, Wt2l, Nn * 32);

    const int gx = (Nn + 63) / 64;
    const int ab = (Nn + 3) / 4;  // 4 waves (nodes) per 256-thread block

    k_gemm_mfma<2><<<2 * gx, 256, 0, stream>>>(Ahi, Alo, Wt0h, Wt0l, dis, Tb, Nn);
    k_agg128<<<ab, 256, 0, stream>>>(Tb, Ahi, Alo, rp, csr, dis, b0, Nn);
    k_gemm_mfma<2><<<2 * gx, 256, 0, stream>>>(Ahi, Alo, Wt1h, Wt1l, dis, Tb, Nn);
    k_agg128<<<ab, 256, 0, stream>>>(Tb, Ahi, Alo, rp, csr, dis, b1, Nn);
    k_gemm_mfma<1><<<gx, 256, 0, stream>>>(Ahi, Alo, Wt2h, Wt2l, dis, Tb, Nn);
    k_agg64<<<ab, 256, 0, stream>>>(Tb, (float*)d_out, rp, csr, dis, b2, Nn);
}